// Round 17
// baseline (98.282 us; speedup 1.0000x reference)
//
#include <hip/hip_runtime.h>

#define BB 32
#define TT 64
#define NN 128
#define FF 128
#define UU 64
#define K1 64
#define K2 32
#define G4 256
#define EPSV 1e-3f
#define SLOPE 0.01f

#define ALD 136
#define SLD 136
#define WLD 72

typedef __attribute__((ext_vector_type(8))) short short8;
typedef __attribute__((ext_vector_type(4))) float f32x4;
typedef __attribute__((ext_vector_type(2))) __fp16 half2v;

__device__ __forceinline__ float sigmoidf_(float x) {
  return __builtin_amdgcn_rcpf(1.f + __expf(-x));
}
__device__ __forceinline__ float tanhf_(float x) {
  return 1.f - 2.f * __builtin_amdgcn_rcpf(__expf(2.f * x) + 1.f);
}
__device__ __forceinline__ float leaky_(float x) { return x >= 0.f ? x : SLOPE * x; }
__device__ __forceinline__ unsigned short f2bf(float x) {
  union { float f; unsigned u; } v; v.f = x;
  unsigned r = v.u + 0x7fff + ((v.u >> 16) & 1);
  return (unsigned short)(r >> 16);
}

// ---------------- K1: xz GEMM (blocks 0..255) + weight packing (256,257) ----------------
__global__ __launch_bounds__(256) void k_xzp(const float* __restrict__ x,
                                             const float* __restrict__ wk,
                                             const float* __restrict__ bias,
                                             const float* __restrict__ wr,
                                             const float* __restrict__ w1,
                                             float* __restrict__ xz,
                                             unsigned* __restrict__ wrp,
                                             unsigned* __restrict__ w1p) {
  int tid = threadIdx.x;
  if (blockIdx.x < 256) {
    __shared__ float xs[8][FF];
    int row0 = blockIdx.x * 8;
    for (int i = tid; i < 8 * FF; i += 256) xs[i >> 7][i & 127] = x[(size_t)row0 * FF + i];
    __syncthreads();
    int g = tid;
    float acc[8];
    float bg = bias[g];
#pragma unroll
    for (int r = 0; r < 8; ++r) acc[r] = bg;
    for (int f = 0; f < FF; ++f) {
      float w = wk[f * G4 + g];
#pragma unroll
      for (int r = 0; r < 8; ++r) acc[r] += xs[r][f] * w;
    }
#pragma unroll
    for (int r = 0; r < 8; ++r) xz[(size_t)(row0 + r) * G4 + g] = acc[r];
  } else if (blockIdx.x == 256) {
    // pack Wr f16x2, lane-contiguous: wrp[u*128 + gate*32 + p]
    for (int idx = tid; idx < 4 * 32 * UU; idx += 256) {
      int p = idx & 31;
      int gate = (idx >> 5) & 3;
      int u = idx >> 7;
      int col = gate * UU + u;
      union { __fp16 h[2]; unsigned u; } pk;
      pk.h[0] = (__fp16)wr[(2 * p) * G4 + col];
      pk.h[1] = (__fp16)wr[(2 * p + 1) * G4 + col];
      wrp[idx] = pk.u;
    }
  } else {
    // pack w1 f16x2, lane-contiguous: w1p[k*32 + p]
    for (int idx = tid; idx < 32 * K1; idx += 256) {
      int p = idx & 31, k = idx >> 5;
      union { __fp16 h[2]; unsigned u; } pk;
      pk.h[0] = (__fp16)w1[(2 * p) * K1 + k];
      pk.h[1] = (__fp16)w1[(2 * p + 1) * K1 + k];
      w1p[idx] = pk.u;
    }
  }
}

// ---------------- K2 mega: scan 4 blocks x 8 wave-batches + prep on idle CUs ----------------
// Scan: wave = batch, barrier-free (round-7 structure: no vmcnt drain ever; xz
// prefetched one step ahead from global). 84 KB LDS pins 1 block/CU -> allocator
// grants the full 256-VGPR budget (round-6/12 lesson) so the 128-dword weight
// array stays resident; 8 waves = 2 waves/SIMD so two batch scans interleave.
// h16 RAW (fp16 write / uint4 read, same wave) pinned with sched_barrier(0).
__global__ __launch_bounds__(512, 1) void k_mega(
    const float* __restrict__ xz, const unsigned* __restrict__ wrp,
    const unsigned* __restrict__ w1p,
    const float* __restrict__ bnl_g, const float* __restrict__ bnl_b,
    const float* __restrict__ bnl_m, const float* __restrict__ bnl_v,
    const float* __restrict__ a, const float* __restrict__ w2,
    const float* __restrict__ d1w,
    float* __restrict__ s1out, float* __restrict__ rsum,
    unsigned short* __restrict__ apad, unsigned short* __restrict__ w2t,
    float4* __restrict__ d1r) {
  __shared__ __align__(16) char smem[86016];  // 84 KB: forces 1 block/CU
  int tid = threadIdx.x;
  int blk = blockIdx.x;

  if (blk < 4) {
    int wave = tid >> 6, lane = tid & 63;
    int b = blk * 8 + wave;
    __fp16* hpw = (__fp16*)smem + (size_t)wave * TT * UU;       // 8 KB per wave
    __fp16* h16w = (__fp16*)(smem + 65536) + wave * UU;         // 128 B per wave

    // weights: lane-contiguous 128 dwords -> 32 dwordx4 loads (register-resident)
    unsigned wv[4][32];
    {
      const uint4* wp = (const uint4*)(wrp + (size_t)lane * 128);
#pragma unroll
      for (int k = 0; k < 32; ++k) {
        uint4 v = wp[k];
        int gate = k >> 3, p0 = (k & 7) * 4;
        wv[gate][p0 + 0] = v.x; wv[gate][p0 + 1] = v.y;
        wv[gate][p0 + 2] = v.z; wv[gate][p0 + 3] = v.w;
      }
    }
    float bscale = bnl_g[lane] * rsqrtf(bnl_v[lane] + EPSV);
    float boff = bnl_b[lane] - bnl_m[lane] * bscale;
    h16w[lane] = (__fp16)0.f;
    float c = 0.f;

    const float* xzb = xz + (size_t)b * TT * G4;
    float cz0 = xzb[lane], cz1 = xzb[64 + lane], cz2 = xzb[128 + lane], cz3 = xzb[192 + lane];

    for (int t = 0; t < TT; ++t) {
      int tn = (t + 1 < TT) ? t + 1 : t;
      const float* nb = xzb + tn * G4;
      float nz0 = nb[lane], nz1 = nb[64 + lane], nz2 = nb[128 + lane], nz3 = nb[192 + lane];
      __builtin_amdgcn_sched_barrier(0);  // h16 reads must not move above prior write
      unsigned hw[32];
      {
        const uint4* hq = (const uint4*)h16w;
#pragma unroll
        for (int k = 0; k < 8; ++k) {
          uint4 v = hq[k];
          hw[4 * k + 0] = v.x; hw[4 * k + 1] = v.y; hw[4 * k + 2] = v.z; hw[4 * k + 3] = v.w;
        }
      }
      float z0 = cz0, z1 = cz1, z2 = cz2, z3 = cz3;
#pragma unroll
      for (int p = 0; p < 32; ++p) {
        half2v hh = __builtin_bit_cast(half2v, hw[p]);
        z0 = __builtin_amdgcn_fdot2(__builtin_bit_cast(half2v, wv[0][p]), hh, z0, false);
        z1 = __builtin_amdgcn_fdot2(__builtin_bit_cast(half2v, wv[1][p]), hh, z1, false);
        z2 = __builtin_amdgcn_fdot2(__builtin_bit_cast(half2v, wv[2][p]), hh, z2, false);
        z3 = __builtin_amdgcn_fdot2(__builtin_bit_cast(half2v, wv[3][p]), hh, z3, false);
      }
      float i_ = sigmoidf_(z0), f_ = sigmoidf_(z1), g_ = tanhf_(z2), o_ = sigmoidf_(z3);
      c = f_ * c + i_ * g_;
      float h = o_ * tanhf_(c);
      h16w[lane] = (__fp16)h;             // wave-private, in-order LDS pipe
      __builtin_amdgcn_sched_barrier(0);  // pin write before next iter's reads
      hpw[t * UU + lane] = (__fp16)(h * bscale + boff);
      cz0 = nz0; cz1 = nz1; cz2 = nz2; cz3 = nz3;
    }

    // s1 tail: per-wave, 64 rows, lane = output column k (no barrier needed)
    unsigned w1v[32];
    {
      const uint4* wp1 = (const uint4*)(w1p + (size_t)lane * 32);
#pragma unroll
      for (int k = 0; k < 8; ++k) {
        uint4 v = wp1[k];
        w1v[4 * k + 0] = v.x; w1v[4 * k + 1] = v.y; w1v[4 * k + 2] = v.z; w1v[4 * k + 3] = v.w;
      }
    }
    float* s1b = s1out + (size_t)b * TT * K1;
    for (int t = 0; t < TT; ++t) {
      unsigned hw2[32];
      {
        const uint4* hq = (const uint4*)(hpw + t * UU);
#pragma unroll
        for (int k = 0; k < 8; ++k) {
          uint4 v = hq[k];
          hw2[4 * k + 0] = v.x; hw2[4 * k + 1] = v.y; hw2[4 * k + 2] = v.z; hw2[4 * k + 3] = v.w;
        }
      }
      float acc = 0.f;
#pragma unroll
      for (int p = 0; p < 32; ++p)
        acc = __builtin_amdgcn_fdot2(__builtin_bit_cast(half2v, w1v[p]),
                                     __builtin_bit_cast(half2v, hw2[p]), acc, false);
      s1b[t * K1 + lane] = acc;
    }
  } else if (blk < 36) {
    int b = blk - 4;
    int wave = tid >> 6, lane = tid & 63;
    const float* ab = a + (size_t)b * NN * NN;
    // 8 waves x 16 rows
    for (int r = 0; r < 16; ++r) {
      int row = wave * 16 + r;
      float2 v = *(const float2*)(ab + (size_t)row * NN + lane * 2);
      float s = v.x + v.y;
#pragma unroll
      for (int off = 32; off >= 1; off >>= 1) s += __shfl_down(s, off);
      if (lane == 0) rsum[b * NN + row] = s;
    }
    unsigned short* ap = apad + (size_t)b * NN * ALD;
    for (int idx = tid; idx < NN * NN; idx += 512) {
      int i = idx >> 7, j = idx & 127;
      ap[i * ALD + j] = f2bf(ab[idx]);
    }
  } else if (blk == 36) {
    for (int idx = tid; idx < K1 * K2; idx += 512) {
      int k = idx >> 5, m = idx & 31;
      w2t[m * WLD + k] = f2bf(w2[idx]);
    }
  } else {
    int t = blk - 37;
    float* dt = (float*)smem;  // 12 KB of the 84
    const float* src = d1w + (size_t)t * NN * K2 * 3;
    for (int c32 = 0; c32 < 4; ++c32) {
      __syncthreads();
      for (int i = tid; i < 768; i += 512)
        ((float4*)dt)[i] = ((const float4*)(src + c32 * 3072))[i];
      __syncthreads();
#pragma unroll
      for (int q = 0; q < 2; ++q) {
        int item = q * 512 + tid;
        if (item < 768) {
          int l = item & 63;
          int gc = item >> 6;
          int g = gc / 3, cc = gc % 3;
          int it = g >> 1, mt = g & 1;
          int l15v = l & 15, l4v = l >> 4;
          int m = mt * 16 + l15v;
          int rowbase = it * 16 + l4v * 4;
          float4 v;
          v.x = dt[(rowbase + 0) * 96 + m * 3 + cc];
          v.y = dt[(rowbase + 1) * 96 + m * 3 + cc];
          v.z = dt[(rowbase + 2) * 96 + m * 3 + cc];
          v.w = dt[(rowbase + 3) * 96 + m * 3 + cc];
          d1r[(((size_t)t * 4 + g) * 3 + cc) * 256 + c32 * 64 + l] = v;
        }
      }
    }
  }
}

// ---------------- fused GCN1+GCN2+d1: register A/B frags + 2 timesteps/block ----------------
__global__ __launch_bounds__(256) void k_gcn(
    const float* __restrict__ s1g, const float* __restrict__ rsum,
    const unsigned short* __restrict__ apad, const unsigned short* __restrict__ w2t,
    const float* __restrict__ b1,
    const float* __restrict__ bn1_g, const float* __restrict__ bn1_b,
    const float* __restrict__ bn1_m, const float* __restrict__ bn1_v,
    const float* __restrict__ b2,
    const float* __restrict__ bn2_g, const float* __restrict__ bn2_b,
    const float* __restrict__ bn2_m, const float* __restrict__ bn2_v,
    const float4* __restrict__ d1r, float* __restrict__ part) {
  __shared__ unsigned short s2_lds[K2 * SLD];  // 8704 B
  __shared__ float s1l[2][K1];
  __shared__ float4 gp[K1];
  __shared__ float r_lds[NN];
  __shared__ float p2[3 * K2];
  __shared__ float red[12];

  int blk = blockIdx.x;
  int b = blk & 31, tg = blk >> 5;   // tg-major
  int t0 = tg * 2;
  int tid = threadIdx.x;
  int lane = tid & 63, wave = tid >> 6;
  int l15 = lane & 15, l4 = lane >> 4;

  const unsigned short* ab = apad + (size_t)b * NN * ALD;
  short8 afrag[4][2];
#pragma unroll
  for (int kt = 0; kt < 4; ++kt)
#pragma unroll
    for (int it = 0; it < 2; ++it) {
      int i = (wave * 2 + it) * 16 + l15;
      afrag[kt][it] = *((const short8*)&ab[i * ALD + kt * 32 + l4 * 8]);
    }
  short8 bw[2][2];
#pragma unroll
  for (int kt = 0; kt < 2; ++kt) {
    bw[kt][0] = *((const short8*)&w2t[(0 + l15) * WLD + kt * 32 + l4 * 8]);
    bw[kt][1] = *((const short8*)&w2t[(16 + l15) * WLD + kt * 32 + l4 * 8]);
  }

  if (tid < 128) ((float*)s1l)[tid] = s1g[((size_t)b * TT + t0) * K1 + tid];
  if (tid < K1) {
    float s = bn1_g[tid] * rsqrtf(bn1_v[tid] + EPSV);
    gp[tid] = make_float4(b1[tid], s, bn1_b[tid] - bn1_m[tid] * s, 0.f);
  }
  if (tid >= 64 && tid < 192) r_lds[tid - 64] = rsum[b * NN + (tid - 64)];
  if (tid >= 192 && tid < 192 + K2) {
    int m = tid - 192;
    float s = bn2_g[m] * rsqrtf(bn2_v[m] + EPSV);
    p2[m] = b2[m];
    p2[K2 + m] = s;
    p2[2 * K2 + m] = bn2_b[m] - bn2_m[m] * s;
  }
  __syncthreads();

  f32x4 z4 = {0.f, 0.f, 0.f, 0.f};
  float rj0 = r_lds[(wave * 2 + 0) * 16 + l15];
  float rj1 = r_lds[(wave * 2 + 1) * 16 + l15];

  float c0 = 0.f, c1 = 0.f, c2 = 0.f;

  for (int ti = 0; ti < 2; ++ti) {
    int t = t0 + ti;
    f32x4 a1[2][2];
    a1[0][0] = z4; a1[0][1] = z4; a1[1][0] = z4; a1[1][1] = z4;
#pragma unroll
    for (int kt = 0; kt < 2; ++kt) {
      float4 gpv[8];
      float s1v[8];
#pragma unroll
      for (int e = 0; e < 8; ++e) {
        gpv[e] = gp[kt * 32 + l4 * 8 + e];
        s1v[e] = s1l[ti][kt * 32 + l4 * 8 + e];
      }
#pragma unroll
      for (int jt = 0; jt < 2; ++jt) {
        float rj = jt ? rj1 : rj0;
        short8 af;
#pragma unroll
        for (int e = 0; e < 8; ++e) {
          float4 p = gpv[e];
          float v = leaky_(rj * s1v[e] + p.x) * p.y + p.z;
          af[e] = (short)f2bf(v);
        }
        a1[jt][0] = __builtin_amdgcn_mfma_f32_16x16x32_bf16(af, bw[kt][0], a1[jt][0], 0, 0, 0);
        a1[jt][1] = __builtin_amdgcn_mfma_f32_16x16x32_bf16(af, bw[kt][1], a1[jt][1], 0, 0, 0);
      }
    }
    __syncthreads();
#pragma unroll
    for (int jt = 0; jt < 2; ++jt) {
      int jbase = (wave * 2 + jt) * 16 + l4 * 4;
#pragma unroll
      for (int mt = 0; mt < 2; ++mt) {
        int m = mt * 16 + l15;
        unsigned lo = (unsigned)f2bf(a1[jt][mt][0]) | ((unsigned)f2bf(a1[jt][mt][1]) << 16);
        unsigned hi = (unsigned)f2bf(a1[jt][mt][2]) | ((unsigned)f2bf(a1[jt][mt][3]) << 16);
        uint2 val; val.x = lo; val.y = hi;
        *((uint2*)&s2_lds[m * SLD + jbase]) = val;
      }
    }
    __syncthreads();

    f32x4 acc[2][2];
    acc[0][0] = z4; acc[0][1] = z4; acc[1][0] = z4; acc[1][1] = z4;
#pragma unroll
    for (int kt = 0; kt < 4; ++kt) {
      short8 bfrag0 = *((const short8*)&s2_lds[(0 + l15) * SLD + kt * 32 + l4 * 8]);
      short8 bfrag1 = *((const short8*)&s2_lds[(16 + l15) * SLD + kt * 32 + l4 * 8]);
#pragma unroll
      for (int it = 0; it < 2; ++it) {
        acc[it][0] = __builtin_amdgcn_mfma_f32_16x16x32_bf16(afrag[kt][it], bfrag0, acc[it][0], 0, 0, 0);
        acc[it][1] = __builtin_amdgcn_mfma_f32_16x16x32_bf16(afrag[kt][it], bfrag1, acc[it][1], 0, 0, 0);
      }
    }
    float gv[2][2][4];
#pragma unroll
    for (int it = 0; it < 2; ++it)
#pragma unroll
      for (int mt = 0; mt < 2; ++mt) {
        int m = mt * 16 + l15;
        float bb = p2[m], bs = p2[K2 + m], bo = p2[2 * K2 + m];
#pragma unroll
        for (int r = 0; r < 4; ++r) gv[it][mt][r] = leaky_(acc[it][mt][r] + bb) * bs + bo;
      }
#pragma unroll
    for (int g = 0; g < 4; ++g) {
      int it = g >> 1, mt = g & 1;
      float4 v0 = d1r[(((size_t)t * 4 + g) * 3 + 0) * 256 + tid];
      float4 v1 = d1r[(((size_t)t * 4 + g) * 3 + 1) * 256 + tid];
      float4 v2 = d1r[(((size_t)t * 4 + g) * 3 + 2) * 256 + tid];
      c0 += gv[it][mt][0] * v0.x + gv[it][mt][1] * v0.y + gv[it][mt][2] * v0.z + gv[it][mt][3] * v0.w;
      c1 += gv[it][mt][0] * v1.x + gv[it][mt][1] * v1.y + gv[it][mt][2] * v1.z + gv[it][mt][3] * v1.w;
      c2 += gv[it][mt][0] * v2.x + gv[it][mt][1] * v2.y + gv[it][mt][2] * v2.z + gv[it][mt][3] * v2.w;
    }
  }

#pragma unroll
  for (int off = 32; off >= 1; off >>= 1) {
    c0 += __shfl_down(c0, off);
    c1 += __shfl_down(c1, off);
    c2 += __shfl_down(c2, off);
  }
  if (lane == 0) { red[wave * 3 + 0] = c0; red[wave * 3 + 1] = c1; red[wave * 3 + 2] = c2; }
  __syncthreads();
  if (tid == 0) {
    float s0 = 0.f, s1v = 0.f, s2v = 0.f;
    for (int w = 0; w < 4; ++w) { s0 += red[w * 3]; s1v += red[w * 3 + 1]; s2v += red[w * 3 + 2]; }
    part[((size_t)b * 32 + tg) * 3 + 0] = s0;
    part[((size_t)b * 32 + tg) * 3 + 1] = s1v;
    part[((size_t)b * 32 + tg) * 3 + 2] = s2v;
  }
}

// ---------------- final: reduce 32 partials, relu, d2 ----------------
__global__ __launch_bounds__(128) void k_out(const float* __restrict__ part,
                                             const float* __restrict__ d1b,
                                             const float* __restrict__ d2w,
                                             const float* __restrict__ d2b,
                                             float* __restrict__ out) {
  int b = blockIdx.x, n = threadIdx.x;
  float s[3] = {0.f, 0.f, 0.f};
  const float* p = part + (size_t)b * 32 * 3;
#pragma unroll
  for (int g = 0; g < 32; ++g) {
    s[0] += p[g * 3];
    s[1] += p[g * 3 + 1];
    s[2] += p[g * 3 + 2];
  }
  float o = d2b[n];
#pragma unroll
  for (int c = 0; c < 3; ++c) {
    float d = s[c] + d1b[c];
    d = d > 0.f ? d : 0.f;
    o += d * d2w[c * NN + n];
  }
  out[b * NN + n] = o;
}

extern "C" void kernel_launch(void* const* d_in, const int* in_sizes, int n_in,
                              void* d_out, int out_size, void* d_ws, size_t ws_size,
                              hipStream_t stream) {
  const float* x      = (const float*)d_in[0];
  const float* a      = (const float*)d_in[1];
  const float* lstm_k = (const float*)d_in[2];
  const float* lstm_r = (const float*)d_in[3];
  const float* lstm_b = (const float*)d_in[4];
  const float* bnl_g  = (const float*)d_in[5];
  const float* bnl_b  = (const float*)d_in[6];
  const float* bnl_m  = (const float*)d_in[7];
  const float* bnl_v  = (const float*)d_in[8];
  const float* w1     = (const float*)d_in[9];
  const float* b1     = (const float*)d_in[10];
  const float* bn1_g  = (const float*)d_in[11];
  const float* bn1_b  = (const float*)d_in[12];
  const float* bn1_m  = (const float*)d_in[13];
  const float* bn1_v  = (const float*)d_in[14];
  const float* w2     = (const float*)d_in[15];
  const float* b2     = (const float*)d_in[16];
  const float* bn2_g  = (const float*)d_in[17];
  const float* bn2_b  = (const float*)d_in[18];
  const float* bn2_m  = (const float*)d_in[19];
  const float* bn2_v  = (const float*)d_in[20];
  const float* d1_w   = (const float*)d_in[21];
  const float* d1_b   = (const float*)d_in[22];
  const float* d2_w   = (const float*)d_in[23];
  const float* d2_b   = (const float*)d_in[24];
  float* out = (float*)d_out;

  char* ws = (char*)d_ws;
  float* xz            = (float*)(ws + 0);                 // 2,097,152 B
  float* s1            = (float*)(ws + 2097152);           //   524,288 B
  float* rsum          = (float*)(ws + 2621440);           //    16,384 B
  float* part          = (float*)(ws + 2637824);           //    24,576 B
  unsigned short* apad = (unsigned short*)(ws + 2662400);  // 1,114,112 B
  unsigned short* w2t  = (unsigned short*)(ws + 3776512);  //     4,608 B
  unsigned* wrp        = (unsigned*)(ws + 3781120);        //    32,768 B
  unsigned* w1p        = (unsigned*)(ws + 3813888);        //     8,192 B
  float4* d1r          = (float4*)(ws + 3822080);          // 3,145,728 B

  k_xzp<<<258, 256, 0, stream>>>(x, lstm_k, lstm_b, lstm_r, w1, xz, wrp, w1p);
  k_mega<<<101, 512, 0, stream>>>(xz, wrp, w1p, bnl_g, bnl_b, bnl_m, bnl_v,
                                  a, w2, d1_w, s1, rsum, apad, w2t, d1r);
  k_gcn<<<1024, 256, 0, stream>>>(s1, rsum, apad, w2t, b1, bn1_g, bn1_b, bn1_m, bn1_v,
                                  b2, bn2_g, bn2_b, bn2_m, bn2_v, d1r, part);
  k_out<<<BB, 128, 0, stream>>>(part, d1_b, d2_w, d2_b, out);
}

// Round 18
// 74.765 us; speedup vs baseline: 1.3145x; 1.3145x over previous
//
#include <hip/hip_runtime.h>

#define BB 32
#define TT 64
#define NN 128
#define FF 128
#define UU 64
#define K1 64
#define K2 32
#define G4 256
#define EPSV 1e-3f
#define SLOPE 0.01f

#define ALD 136
#define SLD 136
#define WLD 72

typedef __attribute__((ext_vector_type(8))) short short8;
typedef __attribute__((ext_vector_type(4))) float f32x4;
typedef __attribute__((ext_vector_type(2))) __fp16 half2v;

__device__ __forceinline__ float sigmoidf_(float x) {
  return __builtin_amdgcn_rcpf(1.f + __expf(-x));
}
__device__ __forceinline__ float tanhf_(float x) {
  return 1.f - 2.f * __builtin_amdgcn_rcpf(__expf(2.f * x) + 1.f);
}
__device__ __forceinline__ float leaky_(float x) { return x >= 0.f ? x : SLOPE * x; }
__device__ __forceinline__ unsigned short f2bf(float x) {
  union { float f; unsigned u; } v; v.f = x;
  unsigned r = v.u + 0x7fff + ((v.u >> 16) & 1);
  return (unsigned short)(r >> 16);
}

// ---------------- K1: xz GEMM (blocks 0..255) + weight packing (256,257) ----------------
__global__ __launch_bounds__(256) void k_xzp(const float* __restrict__ x,
                                             const float* __restrict__ wk,
                                             const float* __restrict__ bias,
                                             const float* __restrict__ wr,
                                             const float* __restrict__ w1,
                                             float* __restrict__ xz,
                                             unsigned* __restrict__ wrp,
                                             unsigned* __restrict__ w1p) {
  int tid = threadIdx.x;
  if (blockIdx.x < 256) {
    __shared__ float xs[8][FF];
    int row0 = blockIdx.x * 8;
    for (int i = tid; i < 8 * FF; i += 256) xs[i >> 7][i & 127] = x[(size_t)row0 * FF + i];
    __syncthreads();
    int g = tid;
    float acc[8];
    float bg = bias[g];
#pragma unroll
    for (int r = 0; r < 8; ++r) acc[r] = bg;
    for (int f = 0; f < FF; ++f) {
      float w = wk[f * G4 + g];
#pragma unroll
      for (int r = 0; r < 8; ++r) acc[r] += xs[r][f] * w;
    }
#pragma unroll
    for (int r = 0; r < 8; ++r) xz[(size_t)(row0 + r) * G4 + g] = acc[r];
  } else if (blockIdx.x == 256) {
    // pack Wr f16x2, lane-contiguous: wrp[u*128 + gate*32 + p]
    for (int idx = tid; idx < 4 * 32 * UU; idx += 256) {
      int p = idx & 31;
      int gate = (idx >> 5) & 3;
      int u = idx >> 7;
      int col = gate * UU + u;
      union { __fp16 h[2]; unsigned u; } pk;
      pk.h[0] = (__fp16)wr[(2 * p) * G4 + col];
      pk.h[1] = (__fp16)wr[(2 * p + 1) * G4 + col];
      wrp[idx] = pk.u;
    }
  } else {
    // pack w1 f16x2, lane-contiguous: w1p[k*32 + p]
    for (int idx = tid; idx < 32 * K1; idx += 256) {
      int p = idx & 31, k = idx >> 5;
      union { __fp16 h[2]; unsigned u; } pk;
      pk.h[0] = (__fp16)w1[(2 * p) * K1 + k];
      pk.h[1] = (__fp16)w1[(2 * p + 1) * K1 + k];
      w1p[idx] = pk.u;
    }
  }
}

// ---------------- K2 mega: gate-split scan (blocks 0..15) + prep (16..112) ----------------
// Scan: 512 thr = 2 batches x 4 gate-waves. Wave (pb,gate) computes only gate
// `gate` for all 64 units (lane = unit): 32 weight dwords + 4-dword h-chunk
// live ≈ 60-65 VGPR -- fits the ~92-VGPR grant that 512-thread launches get
// (rounds 10/11/17: grant never exceeds ~92; this design stops fighting it).
// 8 waves = 2 waves/SIMD genuinely co-resident. One barrier/step (zex exchange,
// parity-dbuf). Per-wave private h16 copy, RAW pinned with sched_barrier(0).
// Gate dot is the same p-ordered chain as rounds 7/8 (absmax-safe ordering).
__global__ __launch_bounds__(512) void k_mega(
    const float* __restrict__ xz, const unsigned* __restrict__ wrp,
    const unsigned* __restrict__ w1p,
    const float* __restrict__ bnl_g, const float* __restrict__ bnl_b,
    const float* __restrict__ bnl_m, const float* __restrict__ bnl_v,
    const float* __restrict__ a, const float* __restrict__ w2,
    const float* __restrict__ d1w,
    float* __restrict__ s1out, float* __restrict__ rsum,
    unsigned short* __restrict__ apad, unsigned short* __restrict__ w2t,
    float4* __restrict__ d1r) {
  __shared__ __align__(16) char smem[21504];  // hp 16K | h16 1K | zex 4K (d1r path uses 12K)
  int tid = threadIdx.x;
  int blk = blockIdx.x;

  if (blk < 16) {
    int wave = tid >> 6, lane = tid & 63;
    int pb = wave >> 2;        // batch within block (0/1)
    int gate = wave & 3;       // this wave's gate
    int b = blk * 2 + pb;
    __fp16* hpw = (__fp16*)smem + (size_t)pb * TT * UU;     // 8 KB per batch
    __fp16* h16w = (__fp16*)(smem + 16384) + wave * UU;     // 128 B per wave
    float* zex = (float*)(smem + 17408);                    // [par][pb][gate*64+lane]

    // weights: 32 contiguous dwords for (unit=lane, gate) -> 8 dwordx4 loads
    unsigned wv[32];
    {
      const uint4* wp = (const uint4*)(wrp + (size_t)lane * 128 + gate * 32);
#pragma unroll
      for (int k = 0; k < 8; ++k) {
        uint4 v = wp[k];
        wv[4 * k + 0] = v.x; wv[4 * k + 1] = v.y; wv[4 * k + 2] = v.z; wv[4 * k + 3] = v.w;
      }
    }
    float bscale = bnl_g[lane] * rsqrtf(bnl_v[lane] + EPSV);
    float boff = bnl_b[lane] - bnl_m[lane] * bscale;
    h16w[lane] = (__fp16)0.f;
    float c = 0.f;

    const float* xzb = xz + (size_t)b * TT * G4;
    float cz = xzb[gate * 64 + lane];   // xz[t=0][gate*64+lane]
    __syncthreads();                    // h16 of all waves inited

    for (int t = 0; t < TT; ++t) {
      int tn = (t + 1 < TT) ? t + 1 : t;
      float nz = xzb[tn * G4 + gate * 64 + lane];  // prefetch; used next iter
      __builtin_amdgcn_sched_barrier(0);  // h16 reads stay after prior write
      float z = cz;
      const uint4* hq = (const uint4*)h16w;
#pragma unroll
      for (int k = 0; k < 8; ++k) {       // consume h in 4-dword chunks (low VGPR)
        uint4 v = hq[k];
        z = __builtin_amdgcn_fdot2(__builtin_bit_cast(half2v, wv[4 * k + 0]),
                                   __builtin_bit_cast(half2v, v.x), z, false);
        z = __builtin_amdgcn_fdot2(__builtin_bit_cast(half2v, wv[4 * k + 1]),
                                   __builtin_bit_cast(half2v, v.y), z, false);
        z = __builtin_amdgcn_fdot2(__builtin_bit_cast(half2v, wv[4 * k + 2]),
                                   __builtin_bit_cast(half2v, v.z), z, false);
        z = __builtin_amdgcn_fdot2(__builtin_bit_cast(half2v, wv[4 * k + 3]),
                                   __builtin_bit_cast(half2v, v.w), z, false);
      }
      int par = t & 1;
      zex[par * 512 + pb * 256 + gate * 64 + lane] = z;
      __syncthreads();   // the only barrier per step
      float zi = zex[par * 512 + pb * 256 + 0 + lane];
      float zf = zex[par * 512 + pb * 256 + 64 + lane];
      float zg = zex[par * 512 + pb * 256 + 128 + lane];
      float zo = zex[par * 512 + pb * 256 + 192 + lane];
      float i_ = sigmoidf_(zi), f_ = sigmoidf_(zf), g_ = tanhf_(zg), o_ = sigmoidf_(zo);
      c = f_ * c + i_ * g_;
      float h = o_ * tanhf_(c);
      h16w[lane] = (__fp16)h;             // wave-private, in-order LDS pipe
      __builtin_amdgcn_sched_barrier(0);  // pin write before next iter's reads
      if (gate == 0) hpw[t * UU + lane] = (__fp16)(h * bscale + boff);
      cz = nz;
    }
    __syncthreads();   // hp complete for both batches

    // s1 tail: wave (pb,gate) does rows t = gate*16 .. gate*16+15 of batch pb
    unsigned w1v[32];
    {
      const uint4* wp1 = (const uint4*)(w1p + (size_t)lane * 32);
#pragma unroll
      for (int k = 0; k < 8; ++k) {
        uint4 v = wp1[k];
        w1v[4 * k + 0] = v.x; w1v[4 * k + 1] = v.y; w1v[4 * k + 2] = v.z; w1v[4 * k + 3] = v.w;
      }
    }
    float* s1b = s1out + (size_t)b * TT * K1;
    for (int r = 0; r < 16; ++r) {
      int t = gate * 16 + r;
      const uint4* hq = (const uint4*)(hpw + t * UU);
      float acc = 0.f;
#pragma unroll
      for (int k = 0; k < 8; ++k) {
        uint4 v = hq[k];
        acc = __builtin_amdgcn_fdot2(__builtin_bit_cast(half2v, w1v[4 * k + 0]),
                                     __builtin_bit_cast(half2v, v.x), acc, false);
        acc = __builtin_amdgcn_fdot2(__builtin_bit_cast(half2v, w1v[4 * k + 1]),
                                     __builtin_bit_cast(half2v, v.y), acc, false);
        acc = __builtin_amdgcn_fdot2(__builtin_bit_cast(half2v, w1v[4 * k + 2]),
                                     __builtin_bit_cast(half2v, v.z), acc, false);
        acc = __builtin_amdgcn_fdot2(__builtin_bit_cast(half2v, w1v[4 * k + 3]),
                                     __builtin_bit_cast(half2v, v.w), acc, false);
      }
      s1b[t * K1 + lane] = acc;
    }
  } else if (blk < 48) {
    int b = blk - 16;
    int wave = tid >> 6, lane = tid & 63;
    const float* ab = a + (size_t)b * NN * NN;
    // 8 waves x 16 rows
    for (int r = 0; r < 16; ++r) {
      int row = wave * 16 + r;
      float2 v = *(const float2*)(ab + (size_t)row * NN + lane * 2);
      float s = v.x + v.y;
#pragma unroll
      for (int off = 32; off >= 1; off >>= 1) s += __shfl_down(s, off);
      if (lane == 0) rsum[b * NN + row] = s;
    }
    unsigned short* ap = apad + (size_t)b * NN * ALD;
    for (int idx = tid; idx < NN * NN; idx += 512) {
      int i = idx >> 7, j = idx & 127;
      ap[i * ALD + j] = f2bf(ab[idx]);
    }
  } else if (blk == 48) {
    for (int idx = tid; idx < K1 * K2; idx += 512) {
      int k = idx >> 5, m = idx & 31;
      w2t[m * WLD + k] = f2bf(w2[idx]);
    }
  } else {
    int t = blk - 49;
    float* dt = (float*)smem;  // 12 KB
    const float* src = d1w + (size_t)t * NN * K2 * 3;
    for (int c32 = 0; c32 < 4; ++c32) {
      __syncthreads();
      for (int i = tid; i < 768; i += 512)
        ((float4*)dt)[i] = ((const float4*)(src + c32 * 3072))[i];
      __syncthreads();
#pragma unroll
      for (int q = 0; q < 2; ++q) {
        int item = q * 512 + tid;
        if (item < 768) {
          int l = item & 63;
          int gc = item >> 6;
          int g = gc / 3, cc = gc % 3;
          int it = g >> 1, mt = g & 1;
          int l15v = l & 15, l4v = l >> 4;
          int m = mt * 16 + l15v;
          int rowbase = it * 16 + l4v * 4;
          float4 v;
          v.x = dt[(rowbase + 0) * 96 + m * 3 + cc];
          v.y = dt[(rowbase + 1) * 96 + m * 3 + cc];
          v.z = dt[(rowbase + 2) * 96 + m * 3 + cc];
          v.w = dt[(rowbase + 3) * 96 + m * 3 + cc];
          d1r[(((size_t)t * 4 + g) * 3 + cc) * 256 + c32 * 64 + l] = v;
        }
      }
    }
  }
}

// ---------------- fused GCN1+GCN2+d1: register A/B frags + 2 timesteps/block ----------------
__global__ __launch_bounds__(256) void k_gcn(
    const float* __restrict__ s1g, const float* __restrict__ rsum,
    const unsigned short* __restrict__ apad, const unsigned short* __restrict__ w2t,
    const float* __restrict__ b1,
    const float* __restrict__ bn1_g, const float* __restrict__ bn1_b,
    const float* __restrict__ bn1_m, const float* __restrict__ bn1_v,
    const float* __restrict__ b2,
    const float* __restrict__ bn2_g, const float* __restrict__ bn2_b,
    const float* __restrict__ bn2_m, const float* __restrict__ bn2_v,
    const float4* __restrict__ d1r, float* __restrict__ part) {
  __shared__ unsigned short s2_lds[K2 * SLD];  // 8704 B
  __shared__ float s1l[2][K1];
  __shared__ float4 gp[K1];
  __shared__ float r_lds[NN];
  __shared__ float p2[3 * K2];
  __shared__ float red[12];

  int blk = blockIdx.x;
  int b = blk & 31, tg = blk >> 5;   // tg-major
  int t0 = tg * 2;
  int tid = threadIdx.x;
  int lane = tid & 63, wave = tid >> 6;
  int l15 = lane & 15, l4 = lane >> 4;

  const unsigned short* ab = apad + (size_t)b * NN * ALD;
  short8 afrag[4][2];
#pragma unroll
  for (int kt = 0; kt < 4; ++kt)
#pragma unroll
    for (int it = 0; it < 2; ++it) {
      int i = (wave * 2 + it) * 16 + l15;
      afrag[kt][it] = *((const short8*)&ab[i * ALD + kt * 32 + l4 * 8]);
    }
  short8 bw[2][2];
#pragma unroll
  for (int kt = 0; kt < 2; ++kt) {
    bw[kt][0] = *((const short8*)&w2t[(0 + l15) * WLD + kt * 32 + l4 * 8]);
    bw[kt][1] = *((const short8*)&w2t[(16 + l15) * WLD + kt * 32 + l4 * 8]);
  }

  if (tid < 128) ((float*)s1l)[tid] = s1g[((size_t)b * TT + t0) * K1 + tid];
  if (tid < K1) {
    float s = bn1_g[tid] * rsqrtf(bn1_v[tid] + EPSV);
    gp[tid] = make_float4(b1[tid], s, bn1_b[tid] - bn1_m[tid] * s, 0.f);
  }
  if (tid >= 64 && tid < 192) r_lds[tid - 64] = rsum[b * NN + (tid - 64)];
  if (tid >= 192 && tid < 192 + K2) {
    int m = tid - 192;
    float s = bn2_g[m] * rsqrtf(bn2_v[m] + EPSV);
    p2[m] = b2[m];
    p2[K2 + m] = s;
    p2[2 * K2 + m] = bn2_b[m] - bn2_m[m] * s;
  }
  __syncthreads();

  f32x4 z4 = {0.f, 0.f, 0.f, 0.f};
  float rj0 = r_lds[(wave * 2 + 0) * 16 + l15];
  float rj1 = r_lds[(wave * 2 + 1) * 16 + l15];

  float c0 = 0.f, c1 = 0.f, c2 = 0.f;

  for (int ti = 0; ti < 2; ++ti) {
    int t = t0 + ti;
    f32x4 a1[2][2];
    a1[0][0] = z4; a1[0][1] = z4; a1[1][0] = z4; a1[1][1] = z4;
#pragma unroll
    for (int kt = 0; kt < 2; ++kt) {
      float4 gpv[8];
      float s1v[8];
#pragma unroll
      for (int e = 0; e < 8; ++e) {
        gpv[e] = gp[kt * 32 + l4 * 8 + e];
        s1v[e] = s1l[ti][kt * 32 + l4 * 8 + e];
      }
#pragma unroll
      for (int jt = 0; jt < 2; ++jt) {
        float rj = jt ? rj1 : rj0;
        short8 af;
#pragma unroll
        for (int e = 0; e < 8; ++e) {
          float4 p = gpv[e];
          float v = leaky_(rj * s1v[e] + p.x) * p.y + p.z;
          af[e] = (short)f2bf(v);
        }
        a1[jt][0] = __builtin_amdgcn_mfma_f32_16x16x32_bf16(af, bw[kt][0], a1[jt][0], 0, 0, 0);
        a1[jt][1] = __builtin_amdgcn_mfma_f32_16x16x32_bf16(af, bw[kt][1], a1[jt][1], 0, 0, 0);
      }
    }
    __syncthreads();
#pragma unroll
    for (int jt = 0; jt < 2; ++jt) {
      int jbase = (wave * 2 + jt) * 16 + l4 * 4;
#pragma unroll
      for (int mt = 0; mt < 2; ++mt) {
        int m = mt * 16 + l15;
        unsigned lo = (unsigned)f2bf(a1[jt][mt][0]) | ((unsigned)f2bf(a1[jt][mt][1]) << 16);
        unsigned hi = (unsigned)f2bf(a1[jt][mt][2]) | ((unsigned)f2bf(a1[jt][mt][3]) << 16);
        uint2 val; val.x = lo; val.y = hi;
        *((uint2*)&s2_lds[m * SLD + jbase]) = val;
      }
    }
    __syncthreads();

    f32x4 acc[2][2];
    acc[0][0] = z4; acc[0][1] = z4; acc[1][0] = z4; acc[1][1] = z4;
#pragma unroll
    for (int kt = 0; kt < 4; ++kt) {
      short8 bfrag0 = *((const short8*)&s2_lds[(0 + l15) * SLD + kt * 32 + l4 * 8]);
      short8 bfrag1 = *((const short8*)&s2_lds[(16 + l15) * SLD + kt * 32 + l4 * 8]);
#pragma unroll
      for (int it = 0; it < 2; ++it) {
        acc[it][0] = __builtin_amdgcn_mfma_f32_16x16x32_bf16(afrag[kt][it], bfrag0, acc[it][0], 0, 0, 0);
        acc[it][1] = __builtin_amdgcn_mfma_f32_16x16x32_bf16(afrag[kt][it], bfrag1, acc[it][1], 0, 0, 0);
      }
    }
    float gv[2][2][4];
#pragma unroll
    for (int it = 0; it < 2; ++it)
#pragma unroll
      for (int mt = 0; mt < 2; ++mt) {
        int m = mt * 16 + l15;
        float bb = p2[m], bs = p2[K2 + m], bo = p2[2 * K2 + m];
#pragma unroll
        for (int r = 0; r < 4; ++r) gv[it][mt][r] = leaky_(acc[it][mt][r] + bb) * bs + bo;
      }
#pragma unroll
    for (int g = 0; g < 4; ++g) {
      int it = g >> 1, mt = g & 1;
      float4 v0 = d1r[(((size_t)t * 4 + g) * 3 + 0) * 256 + tid];
      float4 v1 = d1r[(((size_t)t * 4 + g) * 3 + 1) * 256 + tid];
      float4 v2 = d1r[(((size_t)t * 4 + g) * 3 + 2) * 256 + tid];
      c0 += gv[it][mt][0] * v0.x + gv[it][mt][1] * v0.y + gv[it][mt][2] * v0.z + gv[it][mt][3] * v0.w;
      c1 += gv[it][mt][0] * v1.x + gv[it][mt][1] * v1.y + gv[it][mt][2] * v1.z + gv[it][mt][3] * v1.w;
      c2 += gv[it][mt][0] * v2.x + gv[it][mt][1] * v2.y + gv[it][mt][2] * v2.z + gv[it][mt][3] * v2.w;
    }
  }

#pragma unroll
  for (int off = 32; off >= 1; off >>= 1) {
    c0 += __shfl_down(c0, off);
    c1 += __shfl_down(c1, off);
    c2 += __shfl_down(c2, off);
  }
  if (lane == 0) { red[wave * 3 + 0] = c0; red[wave * 3 + 1] = c1; red[wave * 3 + 2] = c2; }
  __syncthreads();
  if (tid == 0) {
    float s0 = 0.f, s1v = 0.f, s2v = 0.f;
    for (int w = 0; w < 4; ++w) { s0 += red[w * 3]; s1v += red[w * 3 + 1]; s2v += red[w * 3 + 2]; }
    part[((size_t)b * 32 + tg) * 3 + 0] = s0;
    part[((size_t)b * 32 + tg) * 3 + 1] = s1v;
    part[((size_t)b * 32 + tg) * 3 + 2] = s2v;
  }
}

// ---------------- final: reduce 32 partials, relu, d2 ----------------
__global__ __launch_bounds__(128) void k_out(const float* __restrict__ part,
                                             const float* __restrict__ d1b,
                                             const float* __restrict__ d2w,
                                             const float* __restrict__ d2b,
                                             float* __restrict__ out) {
  int b = blockIdx.x, n = threadIdx.x;
  float s[3] = {0.f, 0.f, 0.f};
  const float* p = part + (size_t)b * 32 * 3;
#pragma unroll
  for (int g = 0; g < 32; ++g) {
    s[0] += p[g * 3];
    s[1] += p[g * 3 + 1];
    s[2] += p[g * 3 + 2];
  }
  float o = d2b[n];
#pragma unroll
  for (int c = 0; c < 3; ++c) {
    float d = s[c] + d1b[c];
    d = d > 0.f ? d : 0.f;
    o += d * d2w[c * NN + n];
  }
  out[b * NN + n] = o;
}

extern "C" void kernel_launch(void* const* d_in, const int* in_sizes, int n_in,
                              void* d_out, int out_size, void* d_ws, size_t ws_size,
                              hipStream_t stream) {
  const float* x      = (const float*)d_in[0];
  const float* a      = (const float*)d_in[1];
  const float* lstm_k = (const float*)d_in[2];
  const float* lstm_r = (const float*)d_in[3];
  const float* lstm_b = (const float*)d_in[4];
  const float* bnl_g  = (const float*)d_in[5];
  const float* bnl_b  = (const float*)d_in[6];
  const float* bnl_m  = (const float*)d_in[7];
  const float* bnl_v  = (const float*)d_in[8];
  const float* w1     = (const float*)d_in[9];
  const float* b1     = (const float*)d_in[10];
  const float* bn1_g  = (const float*)d_in[11];
  const float* bn1_b  = (const float*)d_in[12];
  const float* bn1_m  = (const float*)d_in[13];
  const float* bn1_v  = (const float*)d_in[14];
  const float* w2     = (const float*)d_in[15];
  const float* b2     = (const float*)d_in[16];
  const float* bn2_g  = (const float*)d_in[17];
  const float* bn2_b  = (const float*)d_in[18];
  const float* bn2_m  = (const float*)d_in[19];
  const float* bn2_v  = (const float*)d_in[20];
  const float* d1_w   = (const float*)d_in[21];
  const float* d1_b   = (const float*)d_in[22];
  const float* d2_w   = (const float*)d_in[23];
  const float* d2_b   = (const float*)d_in[24];
  float* out = (float*)d_out;

  char* ws = (char*)d_ws;
  float* xz            = (float*)(ws + 0);                 // 2,097,152 B
  float* s1            = (float*)(ws + 2097152);           //   524,288 B
  float* rsum          = (float*)(ws + 2621440);           //    16,384 B
  float* part          = (float*)(ws + 2637824);           //    24,576 B
  unsigned short* apad = (unsigned short*)(ws + 2662400);  // 1,114,112 B
  unsigned short* w2t  = (unsigned short*)(ws + 3776512);  //     4,608 B
  unsigned* wrp        = (unsigned*)(ws + 3781120);        //    32,768 B
  unsigned* w1p        = (unsigned*)(ws + 3813888);        //     8,192 B
  float4* d1r          = (float4*)(ws + 3822080);          // 3,145,728 B

  k_xzp<<<258, 256, 0, stream>>>(x, lstm_k, lstm_b, lstm_r, w1, xz, wrp, w1p);
  k_mega<<<113, 512, 0, stream>>>(xz, wrp, w1p, bnl_g, bnl_b, bnl_m, bnl_v,
                                  a, w2, d1_w, s1, rsum, apad, w2t, d1r);
  k_gcn<<<1024, 256, 0, stream>>>(s1, rsum, apad, w2t, b1, bn1_g, bn1_b, bn1_m, bn1_v,
                                  b2, bn2_g, bn2_b, bn2_m, bn2_v, d1r, part);
  k_out<<<BB, 128, 0, stream>>>(part, d1_b, d2_w, d2_b, out);
}

// Round 19
// 70.440 us; speedup vs baseline: 1.3952x; 1.0614x over previous
//
#include <hip/hip_runtime.h>

#define BB 32
#define TT 64
#define NN 128
#define FF 128
#define UU 64
#define K1 64
#define K2 32
#define G4 256
#define EPSV 1e-3f
#define SLOPE 0.01f

#define ALD 136
#define SLD 136
#define WLD 72

typedef __attribute__((ext_vector_type(8))) short short8;
typedef __attribute__((ext_vector_type(4))) float f32x4;
typedef __attribute__((ext_vector_type(2))) __fp16 half2v;

__device__ __forceinline__ float sigmoidf_(float x) {
  return __builtin_amdgcn_rcpf(1.f + __expf(-x));
}
__device__ __forceinline__ float tanhf_(float x) {
  return 1.f - 2.f * __builtin_amdgcn_rcpf(__expf(2.f * x) + 1.f);
}
__device__ __forceinline__ float leaky_(float x) { return x >= 0.f ? x : SLOPE * x; }
__device__ __forceinline__ unsigned short f2bf(float x) {
  union { float f; unsigned u; } v; v.f = x;
  unsigned r = v.u + 0x7fff + ((v.u >> 16) & 1);
  return (unsigned short)(r >> 16);
}

// ---------------- K1: xz GEMM (blocks 0..255) + weight packing (256,257) ----------------
__global__ __launch_bounds__(256) void k_xzp(const float* __restrict__ x,
                                             const float* __restrict__ wk,
                                             const float* __restrict__ bias,
                                             const float* __restrict__ wr,
                                             const float* __restrict__ w1,
                                             float* __restrict__ xz,
                                             unsigned* __restrict__ wrp,
                                             unsigned* __restrict__ w1p) {
  int tid = threadIdx.x;
  if (blockIdx.x < 256) {
    __shared__ float xs[8][FF];
    int row0 = blockIdx.x * 8;
    for (int i = tid; i < 8 * FF; i += 256) xs[i >> 7][i & 127] = x[(size_t)row0 * FF + i];
    __syncthreads();
    int g = tid;
    float acc[8];
    float bg = bias[g];
#pragma unroll
    for (int r = 0; r < 8; ++r) acc[r] = bg;
    for (int f = 0; f < FF; ++f) {
      float w = wk[f * G4 + g];
#pragma unroll
      for (int r = 0; r < 8; ++r) acc[r] += xs[r][f] * w;
    }
#pragma unroll
    for (int r = 0; r < 8; ++r) xz[(size_t)(row0 + r) * G4 + g] = acc[r];
  } else if (blockIdx.x == 256) {
    // pack Wr f16x2, lane-contiguous: wrp[u*128 + gate*32 + p]
    for (int idx = tid; idx < 4 * 32 * UU; idx += 256) {
      int p = idx & 31;
      int gate = (idx >> 5) & 3;
      int u = idx >> 7;
      int col = gate * UU + u;
      union { __fp16 h[2]; unsigned u; } pk;
      pk.h[0] = (__fp16)wr[(2 * p) * G4 + col];
      pk.h[1] = (__fp16)wr[(2 * p + 1) * G4 + col];
      wrp[idx] = pk.u;
    }
  } else {
    // pack w1 f16x2, lane-contiguous: w1p[k*32 + p]
    for (int idx = tid; idx < 32 * K1; idx += 256) {
      int p = idx & 31, k = idx >> 5;
      union { __fp16 h[2]; unsigned u; } pk;
      pk.h[0] = (__fp16)w1[(2 * p) * K1 + k];
      pk.h[1] = (__fp16)w1[(2 * p + 1) * K1 + k];
      w1p[idx] = pk.u;
    }
  }
}

// ---------------- K2 mega: scan (0..31) + prep on idle CUs (32..128) ----------------
// Round-16 proven structure: 256 thr (N,1) -> full VGPR grant (no spill);
// waves 0/1 role-split the 4 gates (64 weight dwords each), zex parity-dbuf,
// ONE barrier/step, global-free loop; h16 RAW pinned with sched_barrier(0);
// waves 2/3 idle through the loop, join the fused s1 tail.
__global__ __launch_bounds__(256, 1) void k_mega(
    const float* __restrict__ xz, const unsigned* __restrict__ wrp,
    const unsigned* __restrict__ w1p,
    const float* __restrict__ bnl_g, const float* __restrict__ bnl_b,
    const float* __restrict__ bnl_m, const float* __restrict__ bnl_v,
    const float* __restrict__ a, const float* __restrict__ w2,
    const float* __restrict__ d1w,
    float* __restrict__ s1out, float* __restrict__ rsum,
    unsigned short* __restrict__ apad, unsigned short* __restrict__ w2t,
    float4* __restrict__ d1r) {
  __shared__ __align__(16) char smem[76032];
  int tid = threadIdx.x;
  int blk = blockIdx.x;

  if (blk < 32) {
    float* xz_lds = (float*)smem;                    // 64 KB
    __fp16* hp = (__fp16*)(smem + 65536);            // 8 KB
    float* zex = (float*)(smem + 73728);             // 2 KB
    __fp16* h16 = (__fp16*)(smem + 75776);           // 256 B
    int wave = tid >> 6, lane = tid & 63;
    int role = wave & 1;
    int b = blk;

    {  // cooperative xz stage
      const float4* src = (const float4*)(xz + (size_t)b * TT * G4);
      float4* dst = (float4*)xz_lds;
#pragma unroll
      for (int k = 0; k < 16; ++k) dst[tid + k * 256] = src[tid + k * 256];
    }
    unsigned wv0[32], wv1[32];
    if (wave < 2) {
      const uint4* wp = (const uint4*)(wrp + (size_t)lane * 128 + role * 64);
#pragma unroll
      for (int k = 0; k < 8; ++k) {
        uint4 v = wp[k];
        wv0[4 * k + 0] = v.x; wv0[4 * k + 1] = v.y; wv0[4 * k + 2] = v.z; wv0[4 * k + 3] = v.w;
      }
#pragma unroll
      for (int k = 0; k < 8; ++k) {
        uint4 v = wp[8 + k];
        wv1[4 * k + 0] = v.x; wv1[4 * k + 1] = v.y; wv1[4 * k + 2] = v.z; wv1[4 * k + 3] = v.w;
      }
      h16[wave * UU + lane] = (__fp16)0.f;
    }
    float bscale = bnl_g[lane] * rsqrtf(bnl_v[lane] + EPSV);
    float boff = bnl_b[lane] - bnl_m[lane] * bscale;
    float c = 0.f;
    __syncthreads();

    for (int t = 0; t < TT; ++t) {
      int par = t & 1;
      float z0, z1;
      if (wave < 2) {
        __builtin_amdgcn_sched_barrier(0);  // h16 reads must not move above prior write
        unsigned hw[32];
        const uint4* hq = (const uint4*)(h16 + wave * UU);
#pragma unroll
        for (int k = 0; k < 8; ++k) {
          uint4 v = hq[k];
          hw[4 * k + 0] = v.x; hw[4 * k + 1] = v.y; hw[4 * k + 2] = v.z; hw[4 * k + 3] = v.w;
        }
        z0 = xz_lds[t * G4 + role * 128 + lane];
        z1 = xz_lds[t * G4 + role * 128 + 64 + lane];
#pragma unroll
        for (int p = 0; p < 32; ++p) {
          half2v hh = __builtin_bit_cast(half2v, hw[p]);
          z0 = __builtin_amdgcn_fdot2(__builtin_bit_cast(half2v, wv0[p]), hh, z0, false);
          z1 = __builtin_amdgcn_fdot2(__builtin_bit_cast(half2v, wv1[p]), hh, z1, false);
        }
        zex[(par * 2 + role) * 128 + lane] = z0;
        zex[(par * 2 + role) * 128 + 64 + lane] = z1;
      }
      __syncthreads();
      if (wave < 2) {
        float pz0 = zex[(par * 2 + (role ^ 1)) * 128 + lane];
        float pz1 = zex[(par * 2 + (role ^ 1)) * 128 + 64 + lane];
        float zi = role ? pz0 : z0;
        float zf = role ? pz1 : z1;
        float zg = role ? z0 : pz0;
        float zo = role ? z1 : pz1;
        float i_ = sigmoidf_(zi), f_ = sigmoidf_(zf), g_ = tanhf_(zg), o_ = sigmoidf_(zo);
        c = f_ * c + i_ * g_;
        float h = o_ * tanhf_(c);
        h16[wave * UU + lane] = (__fp16)h;
        __builtin_amdgcn_sched_barrier(0);  // pin write before next iter's reads
        if (role == 0) hp[t * UU + lane] = (__fp16)(h * bscale + boff);
      }
    }
    __syncthreads();

    unsigned w1v[32];
    {
      const uint4* wp1 = (const uint4*)(w1p + (size_t)lane * 32);
#pragma unroll
      for (int k = 0; k < 8; ++k) {
        uint4 v = wp1[k];
        w1v[4 * k + 0] = v.x; w1v[4 * k + 1] = v.y; w1v[4 * k + 2] = v.z; w1v[4 * k + 3] = v.w;
      }
    }
    float* s1b = s1out + (size_t)b * TT * K1;
    for (int r = 0; r < 16; ++r) {
      int t = wave * 16 + r;
      unsigned hw2[32];
      const uint4* hq = (const uint4*)(hp + t * UU);
#pragma unroll
      for (int k = 0; k < 8; ++k) {
        uint4 v = hq[k];
        hw2[4 * k + 0] = v.x; hw2[4 * k + 1] = v.y; hw2[4 * k + 2] = v.z; hw2[4 * k + 3] = v.w;
      }
      float acc = 0.f;
#pragma unroll
      for (int p = 0; p < 32; ++p)
        acc = __builtin_amdgcn_fdot2(__builtin_bit_cast(half2v, w1v[p]),
                                     __builtin_bit_cast(half2v, hw2[p]), acc, false);
      s1b[t * K1 + lane] = acc;
    }
  } else if (blk < 64) {
    int b = blk - 32;
    int wave = tid >> 6, lane = tid & 63;
    const float* ab = a + (size_t)b * NN * NN;
    for (int r = 0; r < 32; ++r) {
      int row = wave * 32 + r;
      float2 v = *(const float2*)(ab + (size_t)row * NN + lane * 2);
      float s = v.x + v.y;
#pragma unroll
      for (int off = 32; off >= 1; off >>= 1) s += __shfl_down(s, off);
      if (lane == 0) rsum[b * NN + row] = s;
    }
    unsigned short* ap = apad + (size_t)b * NN * ALD;
    for (int idx = tid; idx < NN * NN; idx += 256) {
      int i = idx >> 7, j = idx & 127;
      ap[i * ALD + j] = f2bf(ab[idx]);
    }
  } else if (blk == 64) {
    for (int idx = tid; idx < K1 * K2; idx += 256) {
      int k = idx >> 5, m = idx & 31;
      w2t[m * WLD + k] = f2bf(w2[idx]);
    }
  } else {
    int t = blk - 65;
    float* dt = (float*)smem;  // 12 KB
    const float* src = d1w + (size_t)t * NN * K2 * 3;
    for (int c32 = 0; c32 < 4; ++c32) {
      __syncthreads();
      for (int i = tid; i < 768; i += 256)
        ((float4*)dt)[i] = ((const float4*)(src + c32 * 3072))[i];
      __syncthreads();
#pragma unroll
      for (int q = 0; q < 3; ++q) {
        int item = q * 256 + tid;
        int l = item & 63;
        int gc = item >> 6;
        int g = gc / 3, cc = gc % 3;
        int it = g >> 1, mt = g & 1;
        int l15v = l & 15, l4v = l >> 4;
        int m = mt * 16 + l15v;
        int rowbase = it * 16 + l4v * 4;
        float4 v;
        v.x = dt[(rowbase + 0) * 96 + m * 3 + cc];
        v.y = dt[(rowbase + 1) * 96 + m * 3 + cc];
        v.z = dt[(rowbase + 2) * 96 + m * 3 + cc];
        v.w = dt[(rowbase + 3) * 96 + m * 3 + cc];
        d1r[(((size_t)t * 4 + g) * 3 + cc) * 256 + c32 * 64 + l] = v;
      }
    }
  }
}

// ---------------- fused GCN1+GCN2+d1: register A/B frags + 4 timesteps/block ----------------
// Round-16 structure with 4 t's per block (512 blocks): afrag/bw/param staging
// amortized 4x; flat fp32 d1 reduction regrouped 16 ways (no recurrent
// amplification -> absmax shift negligible).
__global__ __launch_bounds__(256) void k_gcn(
    const float* __restrict__ s1g, const float* __restrict__ rsum,
    const unsigned short* __restrict__ apad, const unsigned short* __restrict__ w2t,
    const float* __restrict__ b1,
    const float* __restrict__ bn1_g, const float* __restrict__ bn1_b,
    const float* __restrict__ bn1_m, const float* __restrict__ bn1_v,
    const float* __restrict__ b2,
    const float* __restrict__ bn2_g, const float* __restrict__ bn2_b,
    const float* __restrict__ bn2_m, const float* __restrict__ bn2_v,
    const float4* __restrict__ d1r, float* __restrict__ part) {
  __shared__ unsigned short s2_lds[K2 * SLD];  // 8704 B
  __shared__ float s1l[4][K1];                 // 1024 B
  __shared__ float4 gp[K1];
  __shared__ float r_lds[NN];
  __shared__ float p2[3 * K2];
  __shared__ float red[12];

  int blk = blockIdx.x;
  int b = blk & 31, tg = blk >> 5;   // tg-major (tg in [0,16))
  int t0 = tg * 4;
  int tid = threadIdx.x;
  int lane = tid & 63, wave = tid >> 6;
  int l15 = lane & 15, l4 = lane >> 4;

  const unsigned short* ab = apad + (size_t)b * NN * ALD;
  short8 afrag[4][2];
#pragma unroll
  for (int kt = 0; kt < 4; ++kt)
#pragma unroll
    for (int it = 0; it < 2; ++it) {
      int i = (wave * 2 + it) * 16 + l15;
      afrag[kt][it] = *((const short8*)&ab[i * ALD + kt * 32 + l4 * 8]);
    }
  short8 bw[2][2];
#pragma unroll
  for (int kt = 0; kt < 2; ++kt) {
    bw[kt][0] = *((const short8*)&w2t[(0 + l15) * WLD + kt * 32 + l4 * 8]);
    bw[kt][1] = *((const short8*)&w2t[(16 + l15) * WLD + kt * 32 + l4 * 8]);
  }

  ((float*)s1l)[tid] = s1g[((size_t)b * TT + t0) * K1 + tid];  // 256 floats = 4 t's
  if (tid < K1) {
    float s = bn1_g[tid] * rsqrtf(bn1_v[tid] + EPSV);
    gp[tid] = make_float4(b1[tid], s, bn1_b[tid] - bn1_m[tid] * s, 0.f);
  }
  if (tid >= 64 && tid < 192) r_lds[tid - 64] = rsum[b * NN + (tid - 64)];
  if (tid >= 192 && tid < 192 + K2) {
    int m = tid - 192;
    float s = bn2_g[m] * rsqrtf(bn2_v[m] + EPSV);
    p2[m] = b2[m];
    p2[K2 + m] = s;
    p2[2 * K2 + m] = bn2_b[m] - bn2_m[m] * s;
  }
  __syncthreads();

  f32x4 z4 = {0.f, 0.f, 0.f, 0.f};
  float rj0 = r_lds[(wave * 2 + 0) * 16 + l15];
  float rj1 = r_lds[(wave * 2 + 1) * 16 + l15];

  float c0 = 0.f, c1 = 0.f, c2 = 0.f;

  for (int ti = 0; ti < 4; ++ti) {
    int t = t0 + ti;
    f32x4 a1[2][2];
    a1[0][0] = z4; a1[0][1] = z4; a1[1][0] = z4; a1[1][1] = z4;
#pragma unroll
    for (int kt = 0; kt < 2; ++kt) {
      float4 gpv[8];
      float s1v[8];
#pragma unroll
      for (int e = 0; e < 8; ++e) {
        gpv[e] = gp[kt * 32 + l4 * 8 + e];
        s1v[e] = s1l[ti][kt * 32 + l4 * 8 + e];
      }
#pragma unroll
      for (int jt = 0; jt < 2; ++jt) {
        float rj = jt ? rj1 : rj0;
        short8 af;
#pragma unroll
        for (int e = 0; e < 8; ++e) {
          float4 p = gpv[e];
          float v = leaky_(rj * s1v[e] + p.x) * p.y + p.z;
          af[e] = (short)f2bf(v);
        }
        a1[jt][0] = __builtin_amdgcn_mfma_f32_16x16x32_bf16(af, bw[kt][0], a1[jt][0], 0, 0, 0);
        a1[jt][1] = __builtin_amdgcn_mfma_f32_16x16x32_bf16(af, bw[kt][1], a1[jt][1], 0, 0, 0);
      }
    }
    __syncthreads();   // (a) previous t's phase-2 s2_lds reads complete
#pragma unroll
    for (int jt = 0; jt < 2; ++jt) {
      int jbase = (wave * 2 + jt) * 16 + l4 * 4;
#pragma unroll
      for (int mt = 0; mt < 2; ++mt) {
        int m = mt * 16 + l15;
        unsigned lo = (unsigned)f2bf(a1[jt][mt][0]) | ((unsigned)f2bf(a1[jt][mt][1]) << 16);
        unsigned hi = (unsigned)f2bf(a1[jt][mt][2]) | ((unsigned)f2bf(a1[jt][mt][3]) << 16);
        uint2 val; val.x = lo; val.y = hi;
        *((uint2*)&s2_lds[m * SLD + jbase]) = val;
      }
    }
    __syncthreads();   // (b) s2 visible

    f32x4 acc[2][2];
    acc[0][0] = z4; acc[0][1] = z4; acc[1][0] = z4; acc[1][1] = z4;
#pragma unroll
    for (int kt = 0; kt < 4; ++kt) {
      short8 bfrag0 = *((const short8*)&s2_lds[(0 + l15) * SLD + kt * 32 + l4 * 8]);
      short8 bfrag1 = *((const short8*)&s2_lds[(16 + l15) * SLD + kt * 32 + l4 * 8]);
#pragma unroll
      for (int it = 0; it < 2; ++it) {
        acc[it][0] = __builtin_amdgcn_mfma_f32_16x16x32_bf16(afrag[kt][it], bfrag0, acc[it][0], 0, 0, 0);
        acc[it][1] = __builtin_amdgcn_mfma_f32_16x16x32_bf16(afrag[kt][it], bfrag1, acc[it][1], 0, 0, 0);
      }
    }
    float gv[2][2][4];
#pragma unroll
    for (int it = 0; it < 2; ++it)
#pragma unroll
      for (int mt = 0; mt < 2; ++mt) {
        int m = mt * 16 + l15;
        float bb = p2[m], bs = p2[K2 + m], bo = p2[2 * K2 + m];
#pragma unroll
        for (int r = 0; r < 4; ++r) gv[it][mt][r] = leaky_(acc[it][mt][r] + bb) * bs + bo;
      }
#pragma unroll
    for (int g = 0; g < 4; ++g) {
      int it = g >> 1, mt = g & 1;
      float4 v0 = d1r[(((size_t)t * 4 + g) * 3 + 0) * 256 + tid];
      float4 v1 = d1r[(((size_t)t * 4 + g) * 3 + 1) * 256 + tid];
      float4 v2 = d1r[(((size_t)t * 4 + g) * 3 + 2) * 256 + tid];
      c0 += gv[it][mt][0] * v0.x + gv[it][mt][1] * v0.y + gv[it][mt][2] * v0.z + gv[it][mt][3] * v0.w;
      c1 += gv[it][mt][0] * v1.x + gv[it][mt][1] * v1.y + gv[it][mt][2] * v1.z + gv[it][mt][3] * v1.w;
      c2 += gv[it][mt][0] * v2.x + gv[it][mt][1] * v2.y + gv[it][mt][2] * v2.z + gv[it][mt][3] * v2.w;
    }
  }

#pragma unroll
  for (int off = 32; off >= 1; off >>= 1) {
    c0 += __shfl_down(c0, off);
    c1 += __shfl_down(c1, off);
    c2 += __shfl_down(c2, off);
  }
  if (lane == 0) { red[wave * 3 + 0] = c0; red[wave * 3 + 1] = c1; red[wave * 3 + 2] = c2; }
  __syncthreads();
  if (tid == 0) {
    float s0 = 0.f, s1v = 0.f, s2v = 0.f;
    for (int w = 0; w < 4; ++w) { s0 += red[w * 3]; s1v += red[w * 3 + 1]; s2v += red[w * 3 + 2]; }
    part[((size_t)b * 16 + tg) * 3 + 0] = s0;
    part[((size_t)b * 16 + tg) * 3 + 1] = s1v;
    part[((size_t)b * 16 + tg) * 3 + 2] = s2v;
  }
}

// ---------------- final: reduce 16 partials, relu, d2 ----------------
__global__ __launch_bounds__(128) void k_out(const float* __restrict__ part,
                                             const float* __restrict__ d1b,
                                             const float* __restrict__ d2w,
                                             const float* __restrict__ d2b,
                                             float* __restrict__ out) {
  int b = blockIdx.x, n = threadIdx.x;
  float s[3] = {0.f, 0.f, 0.f};
  const float* p = part + (size_t)b * 16 * 3;
#pragma unroll
  for (int g = 0; g < 16; ++g) {
    s[0] += p[g * 3];
    s[1] += p[g * 3 + 1];
    s[2] += p[g * 3 + 2];
  }
  float o = d2b[n];
#pragma unroll
  for (int c = 0; c < 3; ++c) {
    float d = s[c] + d1b[c];
    d = d > 0.f ? d : 0.f;
    o += d * d2w[c * NN + n];
  }
  out[b * NN + n] = o;
}

extern "C" void kernel_launch(void* const* d_in, const int* in_sizes, int n_in,
                              void* d_out, int out_size, void* d_ws, size_t ws_size,
                              hipStream_t stream) {
  const float* x      = (const float*)d_in[0];
  const float* a      = (const float*)d_in[1];
  const float* lstm_k = (const float*)d_in[2];
  const float* lstm_r = (const float*)d_in[3];
  const float* lstm_b = (const float*)d_in[4];
  const float* bnl_g  = (const float*)d_in[5];
  const float* bnl_b  = (const float*)d_in[6];
  const float* bnl_m  = (const float*)d_in[7];
  const float* bnl_v  = (const float*)d_in[8];
  const float* w1     = (const float*)d_in[9];
  const float* b1     = (const float*)d_in[10];
  const float* bn1_g  = (const float*)d_in[11];
  const float* bn1_b  = (const float*)d_in[12];
  const float* bn1_m  = (const float*)d_in[13];
  const float* bn1_v  = (const float*)d_in[14];
  const float* w2     = (const float*)d_in[15];
  const float* b2     = (const float*)d_in[16];
  const float* bn2_g  = (const float*)d_in[17];
  const float* bn2_b  = (const float*)d_in[18];
  const float* bn2_m  = (const float*)d_in[19];
  const float* bn2_v  = (const float*)d_in[20];
  const float* d1_w   = (const float*)d_in[21];
  const float* d1_b   = (const float*)d_in[22];
  const float* d2_w   = (const float*)d_in[23];
  const float* d2_b   = (const float*)d_in[24];
  float* out = (float*)d_out;

  char* ws = (char*)d_ws;
  float* xz            = (float*)(ws + 0);                 // 2,097,152 B
  float* s1            = (float*)(ws + 2097152);           //   524,288 B
  float* rsum          = (float*)(ws + 2621440);           //    16,384 B
  float* part          = (float*)(ws + 2637824);           //    24,576 B
  unsigned short* apad = (unsigned short*)(ws + 2662400);  // 1,114,112 B
  unsigned short* w2t  = (unsigned short*)(ws + 3776512);  //     4,608 B
  unsigned* wrp        = (unsigned*)(ws + 3781120);        //    32,768 B
  unsigned* w1p        = (unsigned*)(ws + 3813888);        //     8,192 B
  float4* d1r          = (float4*)(ws + 3822080);          // 3,145,728 B

  k_xzp<<<258, 256, 0, stream>>>(x, lstm_k, lstm_b, lstm_r, w1, xz, wrp, w1p);
  k_mega<<<129, 256, 0, stream>>>(xz, wrp, w1p, bnl_g, bnl_b, bnl_m, bnl_v,
                                  a, w2, d1_w, s1, rsum, apad, w2t, d1r);
  k_gcn<<<512, 256, 0, stream>>>(s1, rsum, apad, w2t, b1, bn1_g, bn1_b, bn1_m, bn1_v,
                                 b2, bn2_g, bn2_b, bn2_m, bn2_v, d1r, part);
  k_out<<<BB, 128, 0, stream>>>(part, d1_b, d2_w, d2_b, out);
}